// Round 3
// baseline (187.994 us; speedup 1.0000x reference)
//
#include <hip/hip_runtime.h>
#include <math.h>

#define S_NEI 32

// ---------------- transpose 256x256 (WkT[e][f] = Wk[f][e]) ----------------
__global__ __launch_bounds__(256) void transpose256(const float* __restrict__ in,
                                                    float* __restrict__ outT) {
    __shared__ float tile[32][33];
    const int bx = blockIdx.x * 32, by = blockIdx.y * 32;
    const int x = threadIdx.x, y = threadIdx.y;  // 32 x 8
#pragma unroll
    for (int i = 0; i < 32; i += 8)
        tile[y + i][x] = in[(by + y + i) * 256 + bx + x];
    __syncthreads();
#pragma unroll
    for (int i = 0; i < 32; i += 8)
        outT[(bx + y + i) * 256 + by + x] = tile[x][y + i];
}

// ---------------- legacy 8x256 tile GEMM (for tiny precompute GEMMs) -------
template <int KT>
__device__ __forceinline__ void gemm_tile8(const float* __restrict__ A, int row0,
                                           const float* __restrict__ B,
                                           float acc[2][4], float* __restrict__ sA,
                                           float* __restrict__ sB) {
    const int t = threadIdx.x;
    const int tr = t >> 6, tc = t & 63;
    const int r = t >> 5;
    const int k1 = t & 31;
    const size_t arow = (size_t)(row0 + r) * KT;
    for (int kb = 0; kb < KT; kb += 32) {
        sA[k1 * 12 + r] = A[arow + kb + k1];
#pragma unroll
        for (int i = 0; i < 8; ++i) {
            *reinterpret_cast<float4*>(&sB[(i * 4 + tr) * 256 + tc * 4]) =
                *reinterpret_cast<const float4*>(&B[(size_t)(kb + i * 4 + tr) * 256 + tc * 4]);
        }
        __syncthreads();
#pragma unroll
        for (int k = 0; k < 32; ++k) {
            const float2 a2 = *reinterpret_cast<const float2*>(&sA[k * 12 + tr * 2]);
            const float4 b4 = *reinterpret_cast<const float4*>(&sB[k * 256 + tc * 4]);
            acc[0][0] += a2.x * b4.x; acc[0][1] += a2.x * b4.y;
            acc[0][2] += a2.x * b4.z; acc[0][3] += a2.x * b4.w;
            acc[1][0] += a2.y * b4.x; acc[1][1] += a2.y * b4.y;
            acc[1][2] += a2.y * b4.z; acc[1][3] += a2.y * b4.w;
        }
        __syncthreads();
    }
}

// Wqk=Wq@WkT, Wvc=Wv@Wc_top, Wmc=Wm@Wc_bot
__global__ __launch_bounds__(256) void precompute3(const float* __restrict__ Wq,
                                                   const float* __restrict__ Wv,
                                                   const float* __restrict__ Wm,
                                                   const float* __restrict__ Wc,
                                                   const float* __restrict__ WkT,
                                                   float* __restrict__ Wqk,
                                                   float* __restrict__ Wvc,
                                                   float* __restrict__ Wmc) {
    __shared__ float sA[32 * 12];
    __shared__ float sB[32 * 256];
    float acc[2][4] = {};
    const float *Ap, *Bp;
    float* Cp;
    switch (blockIdx.y) {
        case 0: Ap = Wq; Bp = WkT; Cp = Wqk; break;
        case 1: Ap = Wv; Bp = Wc; Cp = Wvc; break;
        default: Ap = Wm; Bp = Wc + 256 * 256; Cp = Wmc; break;
    }
    const int row0 = blockIdx.x * 8;
    gemm_tile8<256>(Ap, row0, Bp, acc, sA, sB);
    const int tr = threadIdx.x >> 6, tc = threadIdx.x & 63;
#pragma unroll
    for (int i = 0; i < 2; ++i) {
        float4 v = make_float4(acc[i][0], acc[i][1], acc[i][2], acc[i][3]);
        *reinterpret_cast<float4*>(&Cp[(row0 + tr * 2 + i) * 256 + tc * 4]) = v;
    }
}

// bqk = bq@WkT ; bfull = bv@Wc_top + bm@Wc_bot + bc  (block per column)
__global__ __launch_bounds__(256) void bias_k(const float* __restrict__ bq,
                                              const float* __restrict__ bv,
                                              const float* __restrict__ bm,
                                              const float* __restrict__ bc,
                                              const float* __restrict__ Wc,
                                              const float* __restrict__ WkT,
                                              float* __restrict__ bqk,
                                              float* __restrict__ bfull) {
    const int c = blockIdx.x;
    const int e = threadIdx.x;
    const int w = e >> 6, l = e & 63;
    float a = bq[e] * WkT[e * 256 + c];
    float v = bv[e] * Wc[e * 256 + c] + bm[e] * Wc[(256 + e) * 256 + c];
    __shared__ float redA[4], redV[4];
#pragma unroll
    for (int off = 32; off; off >>= 1) { a += __shfl_xor(a, off); v += __shfl_xor(v, off); }
    if (l == 0) { redA[w] = a; redV[w] = v; }
    __syncthreads();
    if (e == 0) {
        bqk[c] = redA[0] + redA[1] + redA[2] + redA[3];
        bfull[c] = bc[c] + redV[0] + redV[1] + redV[2] + redV[3];
    }
}

// ---------------- M=16 x N=256 GEMM, A persistent in LDS, B double-buffered
// KT = lda = K. MODE 0: +bias, store. MODE 1: +bias, tanh, row-normalize, store.
template <int KT, bool GATHER, int MODE>
__global__ __launch_bounds__(256) void gemm16(const float* __restrict__ A,
                                              const int* __restrict__ rowidx,
                                              const float* __restrict__ B,
                                              const float* __restrict__ bias,
                                              float* __restrict__ C) {
    constexpr int NS = KT / 32;
    __shared__ float sA[KT * 20];        // [k][r], stride 20 (80B, 16B-aligned)
    __shared__ float sB[2][32 * 256];
    const int t = threadIdx.x;
    const int w = t >> 6, tc = t & 63;
    const int row0 = blockIdx.x * 16;

    // A: 16 rows x KT cols -> sA transposed (once)
    {
        const int r = t & 15;
        const int kc = (t >> 4) * (KT / 16);
        const size_t arow = (size_t)(GATHER ? rowidx[row0 + r] : (row0 + r)) * KT;
#pragma unroll
        for (int u = 0; u < KT / 64; ++u) {
            const float4 v = *reinterpret_cast<const float4*>(&A[arow + kc + u * 4]);
            sA[(kc + u * 4 + 0) * 20 + r] = v.x;
            sA[(kc + u * 4 + 1) * 20 + r] = v.y;
            sA[(kc + u * 4 + 2) * 20 + r] = v.z;
            sA[(kc + u * 4 + 3) * 20 + r] = v.w;
        }
    }

    const int r8 = w * 8;
    const int col4 = tc * 4;
    float4 pb[8];
#pragma unroll
    for (int j = 0; j < 8; ++j)
        pb[j] = *reinterpret_cast<const float4*>(&B[(size_t)(r8 + j) * 256 + col4]);
#pragma unroll
    for (int j = 0; j < 8; ++j)
        *reinterpret_cast<float4*>(&sB[0][(r8 + j) * 256 + col4]) = pb[j];
    __syncthreads();

    float acc[4][4] = {};
    for (int s = 0; s < NS; ++s) {
        const int cur = s & 1;
        if (s + 1 < NS) {
#pragma unroll
            for (int j = 0; j < 8; ++j)
                pb[j] = *reinterpret_cast<const float4*>(
                    &B[(size_t)((s + 1) * 32 + r8 + j) * 256 + col4]);
        }
#pragma unroll
        for (int k = 0; k < 32; ++k) {
            const float4 a4 = *reinterpret_cast<const float4*>(&sA[(s * 32 + k) * 20 + w * 4]);
            const float4 b4 = *reinterpret_cast<const float4*>(&sB[cur][k * 256 + col4]);
            acc[0][0] += a4.x * b4.x; acc[0][1] += a4.x * b4.y; acc[0][2] += a4.x * b4.z; acc[0][3] += a4.x * b4.w;
            acc[1][0] += a4.y * b4.x; acc[1][1] += a4.y * b4.y; acc[1][2] += a4.y * b4.z; acc[1][3] += a4.y * b4.w;
            acc[2][0] += a4.z * b4.x; acc[2][1] += a4.z * b4.y; acc[2][2] += a4.z * b4.z; acc[2][3] += a4.z * b4.w;
            acc[3][0] += a4.w * b4.x; acc[3][1] += a4.w * b4.y; acc[3][2] += a4.w * b4.z; acc[3][3] += a4.w * b4.w;
        }
        if (s + 1 < NS) {
#pragma unroll
            for (int j = 0; j < 8; ++j)
                *reinterpret_cast<float4*>(&sB[cur ^ 1][(r8 + j) * 256 + col4]) = pb[j];
        }
        __syncthreads();
    }

    // epilogue: rows row0 + w*4 + i, cols col4..col4+3
#pragma unroll
    for (int i = 0; i < 4; ++i) {
        float v0 = acc[i][0] + bias[col4 + 0];
        float v1 = acc[i][1] + bias[col4 + 1];
        float v2 = acc[i][2] + bias[col4 + 2];
        float v3 = acc[i][3] + bias[col4 + 3];
        if (MODE == 1) {
            v0 = tanhf(v0); v1 = tanhf(v1); v2 = tanhf(v2); v3 = tanhf(v3);
            float p = v0 * v0 + v1 * v1 + v2 * v2 + v3 * v3;
#pragma unroll
            for (int off = 32; off; off >>= 1) p += __shfl_xor(p, off);
            const float invn = 1.0f / fmaxf(sqrtf(p), 1e-12f);
            v0 *= invn; v1 *= invn; v2 *= invn; v3 *= invn;
        }
        *reinterpret_cast<float4*>(&C[(size_t)(row0 + w * 4 + i) * 256 + col4]) =
            make_float4(v0, v1, v2, v3);
    }
}

// ---------------- per-node: neighbor mean + attention-weighted feature sum --
// rows held in registers; tiny LDS -> high occupancy, deep MLP
__global__ __launch_bounds__(256) void mean_attn(const float* __restrict__ id2feat,
                                                 const int* __restrict__ neigh_mean,
                                                 const int* __restrict__ neigh_attn,
                                                 const float* __restrict__ Qk,
                                                 float* __restrict__ AF) {
    const int b = blockIdx.x;
    const int t = threadIdx.x;
    const int w = t >> 6, l = t & 63;
    __shared__ int sIA[S_NEI], sIM[S_NEI];
    __shared__ float sS[S_NEI];
    __shared__ float4 sRed[2][4][64];  // 8 KB

    if (t < S_NEI) sIA[t] = neigh_attn[b * S_NEI + t];
    else if (t < 2 * S_NEI) sIM[t - S_NEI] = neigh_mean[b * S_NEI + (t - S_NEI)];
    __syncthreads();

    const float4* f4 = reinterpret_cast<const float4*>(id2feat);  // row = 64 float4
    // wave w: attn rows w*8..w*8+7 -> regs; mean rows w*8..w*8+7 -> macc
    float4 r[8];
#pragma unroll
    for (int j = 0; j < 8; ++j) r[j] = f4[(size_t)sIA[w * 8 + j] * 64 + l];
    float4 macc = make_float4(0.f, 0.f, 0.f, 0.f);
#pragma unroll
    for (int j = 0; j < 8; ++j) {
        const float4 v = f4[(size_t)sIM[w * 8 + j] * 64 + l];
        macc.x += v.x; macc.y += v.y; macc.z += v.z; macc.w += v.w;
    }
    const float4 q = reinterpret_cast<const float4*>(Qk + (size_t)b * 256)[l];

    // scores: dot(q, row) reduced over the wave
#pragma unroll
    for (int j = 0; j < 8; ++j) {
        float p = q.x * r[j].x + q.y * r[j].y + q.z * r[j].z + q.w * r[j].w;
#pragma unroll
        for (int off = 32; off; off >>= 1) p += __shfl_xor(p, off);
        if (l == 0) sS[w * 8 + j] = p;
    }
    __syncthreads();

    float m = -1e30f;
#pragma unroll
    for (int s = 0; s < S_NEI; ++s) m = fmaxf(m, sS[s]);
    float sum = 0.f;
#pragma unroll
    for (int s = 0; s < S_NEI; ++s) sum += __expf(sS[s] - m);
    const float inv = 1.0f / sum;

    // weighted partial over this wave's 8 rows
    float4 wa = make_float4(0.f, 0.f, 0.f, 0.f);
#pragma unroll
    for (int j = 0; j < 8; ++j) {
        const float wgt = __expf(sS[w * 8 + j] - m);
        wa.x += wgt * r[j].x; wa.y += wgt * r[j].y; wa.z += wgt * r[j].z; wa.w += wgt * r[j].w;
    }
    sRed[0][w][l] = wa;
    sRed[1][w][l] = macc;
    __syncthreads();

    float4* AF4 = reinterpret_cast<float4*>(AF) + (size_t)b * 128;  // 128 float4/row
    if (t < 64) {
        const float4 a0 = sRed[0][0][t], a1 = sRed[0][1][t], a2 = sRed[0][2][t], a3 = sRed[0][3][t];
        AF4[t] = make_float4((a0.x + a1.x + a2.x + a3.x) * inv,
                             (a0.y + a1.y + a2.y + a3.y) * inv,
                             (a0.z + a1.z + a2.z + a3.z) * inv,
                             (a0.w + a1.w + a2.w + a3.w) * inv);
    } else if (t < 128) {
        const int g = t - 64;
        const float4 a0 = sRed[1][0][g], a1 = sRed[1][1][g], a2 = sRed[1][2][g], a3 = sRed[1][3][g];
        const float sc = 1.0f / S_NEI;
        AF4[64 + g] = make_float4((a0.x + a1.x + a2.x + a3.x) * sc,
                                  (a0.y + a1.y + a2.y + a3.y) * sc,
                                  (a0.z + a1.z + a2.z + a3.z) * sc,
                                  (a0.w + a1.w + a2.w + a3.w) * sc);
    }
}

extern "C" void kernel_launch(void* const* d_in, const int* in_sizes, int n_in,
                              void* d_out, int out_size, void* d_ws, size_t ws_size,
                              hipStream_t stream) {
    const int* nodes      = (const int*)d_in[0];
    const int* neigh_mean = (const int*)d_in[1];
    const int* neigh_attn = (const int*)d_in[2];
    const float* id2feat  = (const float*)d_in[3];
    const float* Wm = (const float*)d_in[4];
    const float* bm = (const float*)d_in[5];
    const float* Wq = (const float*)d_in[6];
    const float* bq = (const float*)d_in[7];
    const float* Wk = (const float*)d_in[8];
    // d_in[9] = bk: cancels in softmax
    const float* Wv = (const float*)d_in[10];
    const float* bv = (const float*)d_in[11];
    const float* Wc = (const float*)d_in[12];
    const float* bc = (const float*)d_in[13];
    float* out = (float*)d_out;

    const int B = in_sizes[0];  // 4096

    float* ws    = (float*)d_ws;
    float* WkT   = ws;                 // 65536
    float* Wqk   = ws + 65536;         // 65536
    float* Wvc   = ws + 131072;        // 65536 } contiguous Wfused[512][256]
    float* Wmc   = ws + 196608;        // 65536 }
    float* bqk   = ws + 262144;        // 256
    float* bfull = ws + 262400;        // 256
    float* Qk    = ws + 262656;        // B*256
    float* AF    = ws + 262656 + B * 256;  // B*512

    transpose256<<<dim3(8, 8), dim3(32, 8), 0, stream>>>(Wk, WkT);
    precompute3<<<dim3(32, 3), 256, 0, stream>>>(Wq, Wv, Wm, Wc, WkT, Wqk, Wvc, Wmc);
    bias_k<<<256, 256, 0, stream>>>(bq, bv, bm, bc, Wc, WkT, bqk, bfull);
    gemm16<256, true, 0><<<B / 16, 256, 0, stream>>>(id2feat, nodes, Wqk, bqk, Qk);
    mean_attn<<<B, 256, 0, stream>>>(id2feat, neigh_mean, neigh_attn, Qk, AF);
    gemm16<512, false, 1><<<B / 16, 256, 0, stream>>>(AF, nullptr, Wvc /*Wfused*/, bfull, out);
}

// Round 4
// 109.477 us; speedup vs baseline: 1.7172x; 1.7172x over previous
//
#include <hip/hip_runtime.h>
#include <math.h>

#define S_NEI 32

// ---------------- transpose 256x256 (WkT[e][f] = Wk[f][e]) ----------------
__global__ __launch_bounds__(256) void transpose256(const float* __restrict__ in,
                                                    float* __restrict__ outT) {
    __shared__ float tile[32][33];
    const int bx = blockIdx.x * 32, by = blockIdx.y * 32;
    const int x = threadIdx.x, y = threadIdx.y;  // 32 x 8
#pragma unroll
    for (int i = 0; i < 32; i += 8)
        tile[y + i][x] = in[(by + y + i) * 256 + bx + x];
    __syncthreads();
#pragma unroll
    for (int i = 0; i < 32; i += 8)
        outT[(bx + y + i) * 256 + by + x] = tile[x][y + i];
}

// ---------------- legacy 8x256 tile GEMM (for tiny precompute GEMMs) -------
template <int KT>
__device__ __forceinline__ void gemm_tile8(const float* __restrict__ A, int row0,
                                           const float* __restrict__ B,
                                           float acc[2][4], float* __restrict__ sA,
                                           float* __restrict__ sB) {
    const int t = threadIdx.x;
    const int tr = t >> 6, tc = t & 63;
    const int r = t >> 5;
    const int k1 = t & 31;
    const size_t arow = (size_t)(row0 + r) * KT;
    for (int kb = 0; kb < KT; kb += 32) {
        sA[k1 * 12 + r] = A[arow + kb + k1];
#pragma unroll
        for (int i = 0; i < 8; ++i) {
            *reinterpret_cast<float4*>(&sB[(i * 4 + tr) * 256 + tc * 4]) =
                *reinterpret_cast<const float4*>(&B[(size_t)(kb + i * 4 + tr) * 256 + tc * 4]);
        }
        __syncthreads();
#pragma unroll
        for (int k = 0; k < 32; ++k) {
            const float2 a2 = *reinterpret_cast<const float2*>(&sA[k * 12 + tr * 2]);
            const float4 b4 = *reinterpret_cast<const float4*>(&sB[k * 256 + tc * 4]);
            acc[0][0] += a2.x * b4.x; acc[0][1] += a2.x * b4.y;
            acc[0][2] += a2.x * b4.z; acc[0][3] += a2.x * b4.w;
            acc[1][0] += a2.y * b4.x; acc[1][1] += a2.y * b4.y;
            acc[1][2] += a2.y * b4.z; acc[1][3] += a2.y * b4.w;
        }
        __syncthreads();
    }
}

// Wqk=Wq@WkT, Wvc=Wv@Wc_top, Wmc=Wm@Wc_bot
__global__ __launch_bounds__(256) void precompute3(const float* __restrict__ Wq,
                                                   const float* __restrict__ Wv,
                                                   const float* __restrict__ Wm,
                                                   const float* __restrict__ Wc,
                                                   const float* __restrict__ WkT,
                                                   float* __restrict__ Wqk,
                                                   float* __restrict__ Wvc,
                                                   float* __restrict__ Wmc) {
    __shared__ float sA[32 * 12];
    __shared__ float sB[32 * 256];
    float acc[2][4] = {};
    const float *Ap, *Bp;
    float* Cp;
    switch (blockIdx.y) {
        case 0: Ap = Wq; Bp = WkT; Cp = Wqk; break;
        case 1: Ap = Wv; Bp = Wc; Cp = Wvc; break;
        default: Ap = Wm; Bp = Wc + 256 * 256; Cp = Wmc; break;
    }
    const int row0 = blockIdx.x * 8;
    gemm_tile8<256>(Ap, row0, Bp, acc, sA, sB);
    const int tr = threadIdx.x >> 6, tc = threadIdx.x & 63;
#pragma unroll
    for (int i = 0; i < 2; ++i) {
        float4 v = make_float4(acc[i][0], acc[i][1], acc[i][2], acc[i][3]);
        *reinterpret_cast<float4*>(&Cp[(row0 + tr * 2 + i) * 256 + tc * 4]) = v;
    }
}

// bqk = bq@WkT ; bfull = bv@Wc_top + bm@Wc_bot + bc  (block per column)
__global__ __launch_bounds__(256) void bias_k(const float* __restrict__ bq,
                                              const float* __restrict__ bv,
                                              const float* __restrict__ bm,
                                              const float* __restrict__ bc,
                                              const float* __restrict__ Wc,
                                              const float* __restrict__ WkT,
                                              float* __restrict__ bqk,
                                              float* __restrict__ bfull) {
    const int c = blockIdx.x;
    const int e = threadIdx.x;
    const int w = e >> 6, l = e & 63;
    float a = bq[e] * WkT[e * 256 + c];
    float v = bv[e] * Wc[e * 256 + c] + bm[e] * Wc[(256 + e) * 256 + c];
    __shared__ float redA[4], redV[4];
#pragma unroll
    for (int off = 32; off; off >>= 1) { a += __shfl_xor(a, off); v += __shfl_xor(v, off); }
    if (l == 0) { redA[w] = a; redV[w] = v; }
    __syncthreads();
    if (e == 0) {
        bqk[c] = redA[0] + redA[1] + redA[2] + redA[3];
        bfull[c] = bc[c] + redV[0] + redV[1] + redV[2] + redV[3];
    }
}

// ---------------- M=16 x N=256 GEMM, barrier-free main loop ----------------
// A (16 rows x KT) staged once to LDS transposed (stride 20 -> b128 broadcast).
// B streamed global->register, 8-deep double-buffered prefetch. No sB, no
// barriers in the k-loop. MODE 0: +bias. MODE 1: +bias, tanh, row-normalize.
#define FMA16(a4, b4)                                                                   \
    do {                                                                                \
        acc[0][0] += (a4).x * (b4).x; acc[0][1] += (a4).x * (b4).y;                     \
        acc[0][2] += (a4).x * (b4).z; acc[0][3] += (a4).x * (b4).w;                     \
        acc[1][0] += (a4).y * (b4).x; acc[1][1] += (a4).y * (b4).y;                     \
        acc[1][2] += (a4).y * (b4).z; acc[1][3] += (a4).y * (b4).w;                     \
        acc[2][0] += (a4).z * (b4).x; acc[2][1] += (a4).z * (b4).y;                     \
        acc[2][2] += (a4).z * (b4).z; acc[2][3] += (a4).z * (b4).w;                     \
        acc[3][0] += (a4).w * (b4).x; acc[3][1] += (a4).w * (b4).y;                     \
        acc[3][2] += (a4).w * (b4).z; acc[3][3] += (a4).w * (b4).w;                     \
    } while (0)

template <int KT, bool GATHER, int MODE>
__global__ __launch_bounds__(256) void gemm16(const float* __restrict__ A,
                                              const int* __restrict__ rowidx,
                                              const float* __restrict__ B,
                                              const float* __restrict__ bias,
                                              float* __restrict__ C) {
    __shared__ float sA[KT * 20];  // [k][r] stride 20 (16B-aligned frags)
    const int t = threadIdx.x;
    const int w = t >> 6, tc = t & 63;
    const int col4 = tc * 4;
    const int row0 = blockIdx.x * 16;

    // stage A transposed, once
    {
        const int r = t & 15;
        const int k0 = (t >> 4) * (KT / 16);
        const size_t arow = (size_t)(GATHER ? rowidx[row0 + r] : (row0 + r)) * KT;
#pragma unroll
        for (int u = 0; u < KT / 64; ++u) {
            const float4 v = *reinterpret_cast<const float4*>(&A[arow + k0 + u * 4]);
            sA[(k0 + u * 4 + 0) * 20 + r] = v.x;
            sA[(k0 + u * 4 + 1) * 20 + r] = v.y;
            sA[(k0 + u * 4 + 2) * 20 + r] = v.z;
            sA[(k0 + u * 4 + 3) * 20 + r] = v.w;
        }
    }
    __syncthreads();

    float acc[4][4] = {};
    float4 bufA[8], bufB[8];
    const float* Bp = B + col4;
#pragma unroll
    for (int j = 0; j < 8; ++j)
        bufA[j] = *reinterpret_cast<const float4*>(&Bp[(size_t)j * 256]);

    for (int kb = 0; kb < KT; kb += 16) {
        // prefetch rows [kb+8, kb+16)
#pragma unroll
        for (int j = 0; j < 8; ++j)
            bufB[j] = *reinterpret_cast<const float4*>(&Bp[(size_t)(kb + 8 + j) * 256]);
        // compute rows [kb, kb+8)
#pragma unroll
        for (int j = 0; j < 8; ++j) {
            const float4 a4 = *reinterpret_cast<const float4*>(&sA[(kb + j) * 20 + w * 4]);
            FMA16(a4, bufA[j]);
        }
        // prefetch rows [kb+16, kb+24)
        if (kb + 16 < KT) {
#pragma unroll
            for (int j = 0; j < 8; ++j)
                bufA[j] = *reinterpret_cast<const float4*>(&Bp[(size_t)(kb + 16 + j) * 256]);
        }
        // compute rows [kb+8, kb+16)
#pragma unroll
        for (int j = 0; j < 8; ++j) {
            const float4 a4 = *reinterpret_cast<const float4*>(&sA[(kb + 8 + j) * 20 + w * 4]);
            FMA16(a4, bufB[j]);
        }
    }

    // epilogue: rows row0 + w*4 + i, cols col4..col4+3
#pragma unroll
    for (int i = 0; i < 4; ++i) {
        float v0 = acc[i][0] + bias[col4 + 0];
        float v1 = acc[i][1] + bias[col4 + 1];
        float v2 = acc[i][2] + bias[col4 + 2];
        float v3 = acc[i][3] + bias[col4 + 3];
        if (MODE == 1) {
            v0 = tanhf(v0); v1 = tanhf(v1); v2 = tanhf(v2); v3 = tanhf(v3);
            float p = v0 * v0 + v1 * v1 + v2 * v2 + v3 * v3;
#pragma unroll
            for (int off = 32; off; off >>= 1) p += __shfl_xor(p, off);
            const float invn = 1.0f / fmaxf(sqrtf(p), 1e-12f);
            v0 *= invn; v1 *= invn; v2 *= invn; v3 *= invn;
        }
        *reinterpret_cast<float4*>(&C[(size_t)(row0 + w * 4 + i) * 256 + col4]) =
            make_float4(v0, v1, v2, v3);
    }
}

// ---------------- per-node: neighbor mean + attention-weighted feature sum --
__global__ __launch_bounds__(256) void mean_attn(const float* __restrict__ id2feat,
                                                 const int* __restrict__ neigh_mean,
                                                 const int* __restrict__ neigh_attn,
                                                 const float* __restrict__ Qk,
                                                 float* __restrict__ AF) {
    const int b = blockIdx.x;
    const int t = threadIdx.x;
    const int w = t >> 6, l = t & 63;
    __shared__ int sIA[S_NEI], sIM[S_NEI];
    __shared__ float sS[S_NEI];
    __shared__ float4 sRed[2][4][64];  // 8 KB

    if (t < S_NEI) sIA[t] = neigh_attn[b * S_NEI + t];
    else if (t < 2 * S_NEI) sIM[t - S_NEI] = neigh_mean[b * S_NEI + (t - S_NEI)];
    __syncthreads();

    const float4* f4 = reinterpret_cast<const float4*>(id2feat);  // row = 64 float4
    float4 r[8];
#pragma unroll
    for (int j = 0; j < 8; ++j) r[j] = f4[(size_t)sIA[w * 8 + j] * 64 + l];
    float4 macc = make_float4(0.f, 0.f, 0.f, 0.f);
#pragma unroll
    for (int j = 0; j < 8; ++j) {
        const float4 v = f4[(size_t)sIM[w * 8 + j] * 64 + l];
        macc.x += v.x; macc.y += v.y; macc.z += v.z; macc.w += v.w;
    }
    const float4 q = reinterpret_cast<const float4*>(Qk + (size_t)b * 256)[l];

#pragma unroll
    for (int j = 0; j < 8; ++j) {
        float p = q.x * r[j].x + q.y * r[j].y + q.z * r[j].z + q.w * r[j].w;
#pragma unroll
        for (int off = 32; off; off >>= 1) p += __shfl_xor(p, off);
        if (l == 0) sS[w * 8 + j] = p;
    }
    __syncthreads();

    float m = -1e30f;
#pragma unroll
    for (int s = 0; s < S_NEI; ++s) m = fmaxf(m, sS[s]);
    float sum = 0.f;
#pragma unroll
    for (int s = 0; s < S_NEI; ++s) sum += __expf(sS[s] - m);
    const float inv = 1.0f / sum;

    float4 wa = make_float4(0.f, 0.f, 0.f, 0.f);
#pragma unroll
    for (int j = 0; j < 8; ++j) {
        const float wgt = __expf(sS[w * 8 + j] - m);
        wa.x += wgt * r[j].x; wa.y += wgt * r[j].y; wa.z += wgt * r[j].z; wa.w += wgt * r[j].w;
    }
    sRed[0][w][l] = wa;
    sRed[1][w][l] = macc;
    __syncthreads();

    float4* AF4 = reinterpret_cast<float4*>(AF) + (size_t)b * 128;  // 128 float4/row
    if (t < 64) {
        const float4 a0 = sRed[0][0][t], a1 = sRed[0][1][t], a2 = sRed[0][2][t], a3 = sRed[0][3][t];
        AF4[t] = make_float4((a0.x + a1.x + a2.x + a3.x) * inv,
                             (a0.y + a1.y + a2.y + a3.y) * inv,
                             (a0.z + a1.z + a2.z + a3.z) * inv,
                             (a0.w + a1.w + a2.w + a3.w) * inv);
    } else if (t < 128) {
        const int g = t - 64;
        const float4 a0 = sRed[1][0][g], a1 = sRed[1][1][g], a2 = sRed[1][2][g], a3 = sRed[1][3][g];
        const float sc = 1.0f / S_NEI;
        AF4[64 + g] = make_float4((a0.x + a1.x + a2.x + a3.x) * sc,
                                  (a0.y + a1.y + a2.y + a3.y) * sc,
                                  (a0.z + a1.z + a2.z + a3.z) * sc,
                                  (a0.w + a1.w + a2.w + a3.w) * sc);
    }
}

extern "C" void kernel_launch(void* const* d_in, const int* in_sizes, int n_in,
                              void* d_out, int out_size, void* d_ws, size_t ws_size,
                              hipStream_t stream) {
    const int* nodes      = (const int*)d_in[0];
    const int* neigh_mean = (const int*)d_in[1];
    const int* neigh_attn = (const int*)d_in[2];
    const float* id2feat  = (const float*)d_in[3];
    const float* Wm = (const float*)d_in[4];
    const float* bm = (const float*)d_in[5];
    const float* Wq = (const float*)d_in[6];
    const float* bq = (const float*)d_in[7];
    const float* Wk = (const float*)d_in[8];
    // d_in[9] = bk: cancels in softmax
    const float* Wv = (const float*)d_in[10];
    const float* bv = (const float*)d_in[11];
    const float* Wc = (const float*)d_in[12];
    const float* bc = (const float*)d_in[13];
    float* out = (float*)d_out;

    const int B = in_sizes[0];  // 4096

    float* ws    = (float*)d_ws;
    float* WkT   = ws;                 // 65536
    float* Wqk   = ws + 65536;         // 65536
    float* Wvc   = ws + 131072;        // 65536 } contiguous Wfused[512][256]
    float* Wmc   = ws + 196608;        // 65536 }
    float* bqk   = ws + 262144;        // 256
    float* bfull = ws + 262400;        // 256
    float* Qk    = ws + 262656;        // B*256
    float* AF    = ws + 262656 + B * 256;  // B*512

    transpose256<<<dim3(8, 8), dim3(32, 8), 0, stream>>>(Wk, WkT);
    precompute3<<<dim3(32, 3), 256, 0, stream>>>(Wq, Wv, Wm, Wc, WkT, Wqk, Wvc, Wmc);
    bias_k<<<256, 256, 0, stream>>>(bq, bv, bm, bc, Wc, WkT, bqk, bfull);
    gemm16<256, true, 0><<<B / 16, 256, 0, stream>>>(id2feat, nodes, Wqk, bqk, Qk);
    mean_attn<<<B, 256, 0, stream>>>(id2feat, neigh_mean, neigh_attn, Qk, AF);
    gemm16<512, false, 1><<<B / 16, 256, 0, stream>>>(AF, nullptr, Wvc /*Wfused*/, bfull, out);
}

// Round 5
// 100.885 us; speedup vs baseline: 1.8634x; 1.0852x over previous
//
#include <hip/hip_runtime.h>
#include <math.h>

#define S_NEI 32

// ---------------- transpose 256x256 (WkT[e][f] = Wk[f][e]) ----------------
__global__ __launch_bounds__(256) void transpose256(const float* __restrict__ in,
                                                    float* __restrict__ outT) {
    __shared__ float tile[32][33];
    const int bx = blockIdx.x * 32, by = blockIdx.y * 32;
    const int x = threadIdx.x, y = threadIdx.y;  // 32 x 8
#pragma unroll
    for (int i = 0; i < 32; i += 8)
        tile[y + i][x] = in[(by + y + i) * 256 + bx + x];
    __syncthreads();
#pragma unroll
    for (int i = 0; i < 32; i += 8)
        outT[(bx + y + i) * 256 + by + x] = tile[x][y + i];
}

// ---------------- legacy 8x256 tile GEMM (for tiny precompute GEMMs) -------
template <int KT>
__device__ __forceinline__ void gemm_tile8(const float* __restrict__ A, int row0,
                                           const float* __restrict__ B,
                                           float acc[2][4], float* __restrict__ sA,
                                           float* __restrict__ sB) {
    const int t = threadIdx.x;
    const int tr = t >> 6, tc = t & 63;
    const int r = t >> 5;
    const int k1 = t & 31;
    const size_t arow = (size_t)(row0 + r) * KT;
    for (int kb = 0; kb < KT; kb += 32) {
        sA[k1 * 12 + r] = A[arow + kb + k1];
#pragma unroll
        for (int i = 0; i < 8; ++i) {
            *reinterpret_cast<float4*>(&sB[(i * 4 + tr) * 256 + tc * 4]) =
                *reinterpret_cast<const float4*>(&B[(size_t)(kb + i * 4 + tr) * 256 + tc * 4]);
        }
        __syncthreads();
#pragma unroll
        for (int k = 0; k < 32; ++k) {
            const float2 a2 = *reinterpret_cast<const float2*>(&sA[k * 12 + tr * 2]);
            const float4 b4 = *reinterpret_cast<const float4*>(&sB[k * 256 + tc * 4]);
            acc[0][0] += a2.x * b4.x; acc[0][1] += a2.x * b4.y;
            acc[0][2] += a2.x * b4.z; acc[0][3] += a2.x * b4.w;
            acc[1][0] += a2.y * b4.x; acc[1][1] += a2.y * b4.y;
            acc[1][2] += a2.y * b4.z; acc[1][3] += a2.y * b4.w;
        }
        __syncthreads();
    }
}

// Wqk=Wq@WkT, Wvc=Wv@Wc_top, Wmc=Wm@Wc_bot
__global__ __launch_bounds__(256) void precompute3(const float* __restrict__ Wq,
                                                   const float* __restrict__ Wv,
                                                   const float* __restrict__ Wm,
                                                   const float* __restrict__ Wc,
                                                   const float* __restrict__ WkT,
                                                   float* __restrict__ Wqk,
                                                   float* __restrict__ Wvc,
                                                   float* __restrict__ Wmc) {
    __shared__ float sA[32 * 12];
    __shared__ float sB[32 * 256];
    float acc[2][4] = {};
    const float *Ap, *Bp;
    float* Cp;
    switch (blockIdx.y) {
        case 0: Ap = Wq; Bp = WkT; Cp = Wqk; break;
        case 1: Ap = Wv; Bp = Wc; Cp = Wvc; break;
        default: Ap = Wm; Bp = Wc + 256 * 256; Cp = Wmc; break;
    }
    const int row0 = blockIdx.x * 8;
    gemm_tile8<256>(Ap, row0, Bp, acc, sA, sB);
    const int tr = threadIdx.x >> 6, tc = threadIdx.x & 63;
#pragma unroll
    for (int i = 0; i < 2; ++i) {
        float4 v = make_float4(acc[i][0], acc[i][1], acc[i][2], acc[i][3]);
        *reinterpret_cast<float4*>(&Cp[(row0 + tr * 2 + i) * 256 + tc * 4]) = v;
    }
}

// bqk = bq@WkT ; bfull = bv@Wc_top + bm@Wc_bot + bc  (block per column)
__global__ __launch_bounds__(256) void bias_k(const float* __restrict__ bq,
                                              const float* __restrict__ bv,
                                              const float* __restrict__ bm,
                                              const float* __restrict__ bc,
                                              const float* __restrict__ Wc,
                                              const float* __restrict__ WkT,
                                              float* __restrict__ bqk,
                                              float* __restrict__ bfull) {
    const int c = blockIdx.x;
    const int e = threadIdx.x;
    const int w = e >> 6, l = e & 63;
    float a = bq[e] * WkT[e * 256 + c];
    float v = bv[e] * Wc[e * 256 + c] + bm[e] * Wc[(256 + e) * 256 + c];
    __shared__ float redA[4], redV[4];
#pragma unroll
    for (int off = 32; off; off >>= 1) { a += __shfl_xor(a, off); v += __shfl_xor(v, off); }
    if (l == 0) { redA[w] = a; redV[w] = v; }
    __syncthreads();
    if (e == 0) {
        bqk[c] = redA[0] + redA[1] + redA[2] + redA[3];
        bfull[c] = bc[c] + redV[0] + redV[1] + redV[2] + redV[3];
    }
}

// ---------------- M=16 x N=256 GEMM, 512 threads, K-split across wave pairs
// A (16 x KT) staged once to LDS transposed; B streamed global->register with
// double-buffered prefetch; no barriers in k-loop. Wave w: A-row-group w&3,
// K-half w>>2. Partials combined via LDS (stride-17, conflict-free).
// MODE 0: +bias. MODE 1: +bias, tanh, row-normalize.
#define FMA16(a4, b4)                                                                   \
    do {                                                                                \
        acc[0][0] += (a4).x * (b4).x; acc[0][1] += (a4).x * (b4).y;                     \
        acc[0][2] += (a4).x * (b4).z; acc[0][3] += (a4).x * (b4).w;                     \
        acc[1][0] += (a4).y * (b4).x; acc[1][1] += (a4).y * (b4).y;                     \
        acc[1][2] += (a4).y * (b4).z; acc[1][3] += (a4).y * (b4).w;                     \
        acc[2][0] += (a4).z * (b4).x; acc[2][1] += (a4).z * (b4).y;                     \
        acc[2][2] += (a4).z * (b4).z; acc[2][3] += (a4).z * (b4).w;                     \
        acc[3][0] += (a4).w * (b4).x; acc[3][1] += (a4).w * (b4).y;                     \
        acc[3][2] += (a4).w * (b4).z; acc[3][3] += (a4).w * (b4).w;                     \
    } while (0)

template <int KT, bool GATHER, int MODE>
__global__ __launch_bounds__(512) void gemm16(const float* __restrict__ A,
                                              const int* __restrict__ rowidx,
                                              const float* __restrict__ B,
                                              const float* __restrict__ bias,
                                              float* __restrict__ C) {
    __shared__ float sA[KT * 20];          // [k][r] stride 20
    __shared__ float sP[4 * 64 * 17];      // partials, stride 17 (17 KB)
    const int t = threadIdx.x;
    const int w = t >> 6;                  // 0..7
    const int aw = w & 3, kh = w >> 2;
    const int tc = t & 63;
    const int col4 = tc * 4;
    const int row0 = blockIdx.x * 16;

    // stage A transposed, once (512 threads: r = t&15, 32 k-chunks)
    {
        const int r = t & 15;
        const int k0 = (t >> 4) * (KT / 32);
#pragma unroll
        for (int u = 0; u < KT / 128; ++u) {
            const size_t arow = (size_t)(GATHER ? rowidx[row0 + r] : (row0 + r)) * KT;
            const float4 v = *reinterpret_cast<const float4*>(&A[arow + k0 + u * 4]);
            sA[(k0 + u * 4 + 0) * 20 + r] = v.x;
            sA[(k0 + u * 4 + 1) * 20 + r] = v.y;
            sA[(k0 + u * 4 + 2) * 20 + r] = v.z;
            sA[(k0 + u * 4 + 3) * 20 + r] = v.w;
        }
    }
    __syncthreads();

    float acc[4][4] = {};
    float4 bufA[8], bufB[8];
    const int kbeg = kh * (KT / 2);
    const float* Bp = B + (size_t)kbeg * 256 + col4;
#pragma unroll
    for (int j = 0; j < 8; ++j)
        bufA[j] = *reinterpret_cast<const float4*>(&Bp[(size_t)j * 256]);

    for (int kb = 0; kb < KT / 2; kb += 16) {
#pragma unroll
        for (int j = 0; j < 8; ++j)
            bufB[j] = *reinterpret_cast<const float4*>(&Bp[(size_t)(kb + 8 + j) * 256]);
#pragma unroll
        for (int j = 0; j < 8; ++j) {
            const float4 a4 =
                *reinterpret_cast<const float4*>(&sA[(kbeg + kb + j) * 20 + aw * 4]);
            FMA16(a4, bufA[j]);
        }
        if (kb + 16 < KT / 2) {
#pragma unroll
            for (int j = 0; j < 8; ++j)
                bufA[j] = *reinterpret_cast<const float4*>(&Bp[(size_t)(kb + 16 + j) * 256]);
        }
#pragma unroll
        for (int j = 0; j < 8; ++j) {
            const float4 a4 =
                *reinterpret_cast<const float4*>(&sA[(kbeg + kb + 8 + j) * 20 + aw * 4]);
            FMA16(a4, bufB[j]);
        }
    }

    // combine K-halves: kh==1 writes partials, kh==0 adds and finishes
    if (kh == 1) {
        float* p = &sP[(aw * 64 + tc) * 17];
#pragma unroll
        for (int i = 0; i < 4; ++i)
#pragma unroll
            for (int c = 0; c < 4; ++c) p[i * 4 + c] = acc[i][c];
    }
    __syncthreads();
    if (kh == 0) {
        const float* p = &sP[(aw * 64 + tc) * 17];
#pragma unroll
        for (int i = 0; i < 4; ++i) {
            float v0 = acc[i][0] + p[i * 4 + 0] + bias[col4 + 0];
            float v1 = acc[i][1] + p[i * 4 + 1] + bias[col4 + 1];
            float v2 = acc[i][2] + p[i * 4 + 2] + bias[col4 + 2];
            float v3 = acc[i][3] + p[i * 4 + 3] + bias[col4 + 3];
            if (MODE == 1) {
                v0 = tanhf(v0); v1 = tanhf(v1); v2 = tanhf(v2); v3 = tanhf(v3);
                float pw = v0 * v0 + v1 * v1 + v2 * v2 + v3 * v3;
#pragma unroll
                for (int off = 32; off; off >>= 1) pw += __shfl_xor(pw, off);
                const float invn = 1.0f / fmaxf(sqrtf(pw), 1e-12f);
                v0 *= invn; v1 *= invn; v2 *= invn; v3 *= invn;
            }
            *reinterpret_cast<float4*>(&C[(size_t)(row0 + aw * 4 + i) * 256 + col4]) =
                make_float4(v0, v1, v2, v3);
        }
    }
}

// ---------------- per-node: neighbor mean + attention-weighted feature sum --
__global__ __launch_bounds__(256) void mean_attn(const float* __restrict__ id2feat,
                                                 const int* __restrict__ neigh_mean,
                                                 const int* __restrict__ neigh_attn,
                                                 const float* __restrict__ Qk,
                                                 float* __restrict__ AF) {
    const int b = blockIdx.x;
    const int t = threadIdx.x;
    const int w = t >> 6, l = t & 63;
    __shared__ int sIA[S_NEI], sIM[S_NEI];
    __shared__ float sS[S_NEI];
    __shared__ float4 sRed[2][4][64];  // 8 KB

    if (t < S_NEI) sIA[t] = neigh_attn[b * S_NEI + t];
    else if (t < 2 * S_NEI) sIM[t - S_NEI] = neigh_mean[b * S_NEI + (t - S_NEI)];
    __syncthreads();

    const float4* f4 = reinterpret_cast<const float4*>(id2feat);  // row = 64 float4
    float4 r[8];
#pragma unroll
    for (int j = 0; j < 8; ++j) r[j] = f4[(size_t)sIA[w * 8 + j] * 64 + l];
    float4 macc = make_float4(0.f, 0.f, 0.f, 0.f);
#pragma unroll
    for (int j = 0; j < 8; ++j) {
        const float4 v = f4[(size_t)sIM[w * 8 + j] * 64 + l];
        macc.x += v.x; macc.y += v.y; macc.z += v.z; macc.w += v.w;
    }
    const float4 q = reinterpret_cast<const float4*>(Qk + (size_t)b * 256)[l];

#pragma unroll
    for (int j = 0; j < 8; ++j) {
        float p = q.x * r[j].x + q.y * r[j].y + q.z * r[j].z + q.w * r[j].w;
#pragma unroll
        for (int off = 32; off; off >>= 1) p += __shfl_xor(p, off);
        if (l == 0) sS[w * 8 + j] = p;
    }
    __syncthreads();

    float m = -1e30f;
#pragma unroll
    for (int s = 0; s < S_NEI; ++s) m = fmaxf(m, sS[s]);
    float sum = 0.f;
#pragma unroll
    for (int s = 0; s < S_NEI; ++s) sum += __expf(sS[s] - m);
    const float inv = 1.0f / sum;

    float4 wa = make_float4(0.f, 0.f, 0.f, 0.f);
#pragma unroll
    for (int j = 0; j < 8; ++j) {
        const float wgt = __expf(sS[w * 8 + j] - m);
        wa.x += wgt * r[j].x; wa.y += wgt * r[j].y; wa.z += wgt * r[j].z; wa.w += wgt * r[j].w;
    }
    sRed[0][w][l] = wa;
    sRed[1][w][l] = macc;
    __syncthreads();

    float4* AF4 = reinterpret_cast<float4*>(AF) + (size_t)b * 128;  // 128 float4/row
    if (t < 64) {
        const float4 a0 = sRed[0][0][t], a1 = sRed[0][1][t], a2 = sRed[0][2][t], a3 = sRed[0][3][t];
        AF4[t] = make_float4((a0.x + a1.x + a2.x + a3.x) * inv,
                             (a0.y + a1.y + a2.y + a3.y) * inv,
                             (a0.z + a1.z + a2.z + a3.z) * inv,
                             (a0.w + a1.w + a2.w + a3.w) * inv);
    } else if (t < 128) {
        const int g = t - 64;
        const float4 a0 = sRed[1][0][g], a1 = sRed[1][1][g], a2 = sRed[1][2][g], a3 = sRed[1][3][g];
        const float sc = 1.0f / S_NEI;
        AF4[64 + g] = make_float4((a0.x + a1.x + a2.x + a3.x) * sc,
                                  (a0.y + a1.y + a2.y + a3.y) * sc,
                                  (a0.z + a1.z + a2.z + a3.z) * sc,
                                  (a0.w + a1.w + a2.w + a3.w) * sc);
    }
}

extern "C" void kernel_launch(void* const* d_in, const int* in_sizes, int n_in,
                              void* d_out, int out_size, void* d_ws, size_t ws_size,
                              hipStream_t stream) {
    const int* nodes      = (const int*)d_in[0];
    const int* neigh_mean = (const int*)d_in[1];
    const int* neigh_attn = (const int*)d_in[2];
    const float* id2feat  = (const float*)d_in[3];
    const float* Wm = (const float*)d_in[4];
    const float* bm = (const float*)d_in[5];
    const float* Wq = (const float*)d_in[6];
    const float* bq = (const float*)d_in[7];
    const float* Wk = (const float*)d_in[8];
    // d_in[9] = bk: cancels in softmax
    const float* Wv = (const float*)d_in[10];
    const float* bv = (const float*)d_in[11];
    const float* Wc = (const float*)d_in[12];
    const float* bc = (const float*)d_in[13];
    float* out = (float*)d_out;

    const int B = in_sizes[0];  // 4096

    float* ws    = (float*)d_ws;
    float* WkT   = ws;                 // 65536
    float* Wqk   = ws + 65536;         // 65536
    float* Wvc   = ws + 131072;        // 65536 } contiguous Wfused[512][256]
    float* Wmc   = ws + 196608;        // 65536 }
    float* bqk   = ws + 262144;        // 256
    float* bfull = ws + 262400;        // 256
    float* Qk    = ws + 262656;        // B*256
    float* AF    = ws + 262656 + B * 256;  // B*512

    transpose256<<<dim3(8, 8), dim3(32, 8), 0, stream>>>(Wk, WkT);
    precompute3<<<dim3(32, 3), 256, 0, stream>>>(Wq, Wv, Wm, Wc, WkT, Wqk, Wvc, Wmc);
    bias_k<<<256, 256, 0, stream>>>(bq, bv, bm, bc, Wc, WkT, bqk, bfull);
    gemm16<256, true, 0><<<B / 16, 512, 0, stream>>>(id2feat, nodes, Wqk, bqk, Qk);
    mean_attn<<<B, 256, 0, stream>>>(id2feat, neigh_mean, neigh_attn, Qk, AF);
    gemm16<512, false, 1><<<B / 16, 512, 0, stream>>>(AF, nullptr, Wvc /*Wfused*/, bfull, out);
}

// Round 6
// 94.003 us; speedup vs baseline: 1.9999x; 1.0732x over previous
//
#include <hip/hip_runtime.h>
#include <math.h>

#define S_NEI 32

// ---------------- transpose 256x256 (WkT[e][f] = Wk[f][e]) ----------------
__global__ __launch_bounds__(256) void transpose256(const float* __restrict__ in,
                                                    float* __restrict__ outT) {
    __shared__ float tile[32][33];
    const int bx = blockIdx.x * 32, by = blockIdx.y * 32;
    const int x = threadIdx.x, y = threadIdx.y;  // 32 x 8
#pragma unroll
    for (int i = 0; i < 32; i += 8)
        tile[y + i][x] = in[(by + y + i) * 256 + bx + x];
    __syncthreads();
#pragma unroll
    for (int i = 0; i < 32; i += 8)
        outT[(bx + y + i) * 256 + by + x] = tile[x][y + i];
}

// ---------------- legacy 8x256 tile GEMM (for tiny precompute GEMMs) -------
template <int KT>
__device__ __forceinline__ void gemm_tile8(const float* __restrict__ A, int row0,
                                           const float* __restrict__ B,
                                           float acc[2][4], float* __restrict__ sA,
                                           float* __restrict__ sB) {
    const int t = threadIdx.x;
    const int tr = t >> 6, tc = t & 63;
    const int r = t >> 5;
    const int k1 = t & 31;
    const size_t arow = (size_t)(row0 + r) * KT;
    for (int kb = 0; kb < KT; kb += 32) {
        sA[k1 * 12 + r] = A[arow + kb + k1];
#pragma unroll
        for (int i = 0; i < 8; ++i) {
            *reinterpret_cast<float4*>(&sB[(i * 4 + tr) * 256 + tc * 4]) =
                *reinterpret_cast<const float4*>(&B[(size_t)(kb + i * 4 + tr) * 256 + tc * 4]);
        }
        __syncthreads();
#pragma unroll
        for (int k = 0; k < 32; ++k) {
            const float2 a2 = *reinterpret_cast<const float2*>(&sA[k * 12 + tr * 2]);
            const float4 b4 = *reinterpret_cast<const float4*>(&sB[k * 256 + tc * 4]);
            acc[0][0] += a2.x * b4.x; acc[0][1] += a2.x * b4.y;
            acc[0][2] += a2.x * b4.z; acc[0][3] += a2.x * b4.w;
            acc[1][0] += a2.y * b4.x; acc[1][1] += a2.y * b4.y;
            acc[1][2] += a2.y * b4.z; acc[1][3] += a2.y * b4.w;
        }
        __syncthreads();
    }
}

// Wqk=Wq@WkT, Wvc=Wv@Wc_top, Wmc=Wm@Wc_bot
__global__ __launch_bounds__(256) void precompute3(const float* __restrict__ Wq,
                                                   const float* __restrict__ Wv,
                                                   const float* __restrict__ Wm,
                                                   const float* __restrict__ Wc,
                                                   const float* __restrict__ WkT,
                                                   float* __restrict__ Wqk,
                                                   float* __restrict__ Wvc,
                                                   float* __restrict__ Wmc) {
    __shared__ float sA[32 * 12];
    __shared__ float sB[32 * 256];
    float acc[2][4] = {};
    const float *Ap, *Bp;
    float* Cp;
    switch (blockIdx.y) {
        case 0: Ap = Wq; Bp = WkT; Cp = Wqk; break;
        case 1: Ap = Wv; Bp = Wc; Cp = Wvc; break;
        default: Ap = Wm; Bp = Wc + 256 * 256; Cp = Wmc; break;
    }
    const int row0 = blockIdx.x * 8;
    gemm_tile8<256>(Ap, row0, Bp, acc, sA, sB);
    const int tr = threadIdx.x >> 6, tc = threadIdx.x & 63;
#pragma unroll
    for (int i = 0; i < 2; ++i) {
        float4 v = make_float4(acc[i][0], acc[i][1], acc[i][2], acc[i][3]);
        *reinterpret_cast<float4*>(&Cp[(row0 + tr * 2 + i) * 256 + tc * 4]) = v;
    }
}

// bqk = bq@WkT ; bfull = bv@Wc_top + bm@Wc_bot + bc  (block per column)
__global__ __launch_bounds__(256) void bias_k(const float* __restrict__ bq,
                                              const float* __restrict__ bv,
                                              const float* __restrict__ bm,
                                              const float* __restrict__ bc,
                                              const float* __restrict__ Wc,
                                              const float* __restrict__ WkT,
                                              float* __restrict__ bqk,
                                              float* __restrict__ bfull) {
    const int c = blockIdx.x;
    const int e = threadIdx.x;
    const int w = e >> 6, l = e & 63;
    float a = bq[e] * WkT[e * 256 + c];
    float v = bv[e] * Wc[e * 256 + c] + bm[e] * Wc[(256 + e) * 256 + c];
    __shared__ float redA[4], redV[4];
#pragma unroll
    for (int off = 32; off; off >>= 1) { a += __shfl_xor(a, off); v += __shfl_xor(v, off); }
    if (l == 0) { redA[w] = a; redV[w] = v; }
    __syncthreads();
    if (e == 0) {
        bqk[c] = redA[0] + redA[1] + redA[2] + redA[3];
        bfull[c] = bc[c] + redV[0] + redV[1] + redV[2] + redV[3];
    }
}

// ---------------- fused per-8-node megakernel ------------------------------
// Phase 1: Qk tile = self_feats(8x256) @ Wqk + bqk      (K-split over 4 waves)
// Phase 2: attention + mean (wave owns 2 nodes, rows in registers)
// Phase 3: out = normalize(tanh(AF(8x512) @ Wfused + bfull))  (K-split)
#define FMA8(a0, a1, b4)                                                   \
    do {                                                                   \
        acc[0][0] += (a0).x * (b4).x; acc[0][1] += (a0).x * (b4).y;        \
        acc[0][2] += (a0).x * (b4).z; acc[0][3] += (a0).x * (b4).w;        \
        acc[1][0] += (a0).y * (b4).x; acc[1][1] += (a0).y * (b4).y;        \
        acc[1][2] += (a0).y * (b4).z; acc[1][3] += (a0).y * (b4).w;        \
        acc[2][0] += (a0).z * (b4).x; acc[2][1] += (a0).z * (b4).y;        \
        acc[2][2] += (a0).z * (b4).z; acc[2][3] += (a0).z * (b4).w;        \
        acc[3][0] += (a0).w * (b4).x; acc[3][1] += (a0).w * (b4).y;        \
        acc[3][2] += (a0).w * (b4).z; acc[3][3] += (a0).w * (b4).w;        \
        acc[4][0] += (a1).x * (b4).x; acc[4][1] += (a1).x * (b4).y;        \
        acc[4][2] += (a1).x * (b4).z; acc[4][3] += (a1).x * (b4).w;        \
        acc[5][0] += (a1).y * (b4).x; acc[5][1] += (a1).y * (b4).y;        \
        acc[5][2] += (a1).y * (b4).z; acc[5][3] += (a1).y * (b4).w;        \
        acc[6][0] += (a1).z * (b4).x; acc[6][1] += (a1).z * (b4).y;        \
        acc[6][2] += (a1).z * (b4).z; acc[6][3] += (a1).z * (b4).w;        \
        acc[7][0] += (a1).w * (b4).x; acc[7][1] += (a1).w * (b4).y;        \
        acc[7][2] += (a1).w * (b4).z; acc[7][3] += (a1).w * (b4).w;        \
    } while (0)

__global__ __launch_bounds__(256, 2) void fused8(const float* __restrict__ id2feat,
                                                 const int* __restrict__ nodes,
                                                 const int* __restrict__ neigh_mean,
                                                 const int* __restrict__ neigh_attn,
                                                 const float* __restrict__ Wqk,
                                                 const float* __restrict__ bqk,
                                                 const float* __restrict__ Wfused,
                                                 const float* __restrict__ bfull,
                                                 float* __restrict__ out) {
    // LDS: [0,24576) sA (phase1, 256x12) / sAF (phase3, 512x12)  [aliased]
    //      [24576,49536) sP partials 3x8x260
    //      [49536,57856) sQk 8x260
    //      [57856,+1024) sIA, [58880,+1024) sIM
    __shared__ __align__(16) char smem[59904];
    float* sA  = (float*)smem;
    float* sAF = (float*)smem;
    float* sP  = (float*)(smem + 24576);
    float* sQk = (float*)(smem + 49536);
    int*   sIA = (int*)(smem + 57856);
    int*   sIM = (int*)(smem + 58880);

    const int t = threadIdx.x;
    const int w = t >> 6, l = t & 63;
    const int col4 = l * 4;
    const int row0 = blockIdx.x * 8;

    sIA[t] = neigh_attn[(size_t)row0 * S_NEI + t];
    sIM[t] = neigh_mean[(size_t)row0 * S_NEI + t];

    // stage 8 self rows transposed: sA[k*12 + r]
    {
        const int r = t & 7;
        const int k0 = (t >> 3) * 8;
        const size_t arow = (size_t)nodes[row0 + r] * 256;
#pragma unroll
        for (int u = 0; u < 2; ++u) {
            const float4 v = *reinterpret_cast<const float4*>(&id2feat[arow + k0 + u * 4]);
            sA[(k0 + u * 4 + 0) * 12 + r] = v.x;
            sA[(k0 + u * 4 + 1) * 12 + r] = v.y;
            sA[(k0 + u * 4 + 2) * 12 + r] = v.z;
            sA[(k0 + u * 4 + 3) * 12 + r] = v.w;
        }
    }
    __syncthreads();

    float acc[8][4] = {};

    // ---- phase 1: wave w does K-quarter [w*64, w*64+64) of Qk GEMM ----
    {
        const int kbeg = w * 64;
        const float* Bp = Wqk + (size_t)kbeg * 256 + col4;
        float4 bufA[8], bufB[8];
#pragma unroll
        for (int j = 0; j < 8; ++j)
            bufA[j] = *reinterpret_cast<const float4*>(&Bp[(size_t)j * 256]);
        for (int kb = 0; kb < 64; kb += 16) {
#pragma unroll
            for (int j = 0; j < 8; ++j)
                bufB[j] = *reinterpret_cast<const float4*>(&Bp[(size_t)(kb + 8 + j) * 256]);
#pragma unroll
            for (int j = 0; j < 8; ++j) {
                const int k = kbeg + kb + j;
                const float4 a0 = *reinterpret_cast<const float4*>(&sA[k * 12]);
                const float4 a1 = *reinterpret_cast<const float4*>(&sA[k * 12 + 4]);
                FMA8(a0, a1, bufA[j]);
            }
            if (kb + 16 < 64) {
#pragma unroll
                for (int j = 0; j < 8; ++j)
                    bufA[j] = *reinterpret_cast<const float4*>(&Bp[(size_t)(kb + 16 + j) * 256]);
            }
#pragma unroll
            for (int j = 0; j < 8; ++j) {
                const int k = kbeg + kb + 8 + j;
                const float4 a0 = *reinterpret_cast<const float4*>(&sA[k * 12]);
                const float4 a1 = *reinterpret_cast<const float4*>(&sA[k * 12 + 4]);
                FMA8(a0, a1, bufB[j]);
            }
        }
    }
    if (w > 0) {
#pragma unroll
        for (int i = 0; i < 8; ++i)
            *reinterpret_cast<float4*>(&sP[(w - 1) * 2080 + i * 260 + col4]) =
                make_float4(acc[i][0], acc[i][1], acc[i][2], acc[i][3]);
    }
    __syncthreads();
    if (w == 0) {
        const float4 bq4 = *reinterpret_cast<const float4*>(&bqk[col4]);
#pragma unroll
        for (int i = 0; i < 8; ++i) {
            float4 v = make_float4(acc[i][0] + bq4.x, acc[i][1] + bq4.y,
                                   acc[i][2] + bq4.z, acc[i][3] + bq4.w);
#pragma unroll
            for (int pw = 0; pw < 3; ++pw) {
                const float4 p =
                    *reinterpret_cast<const float4*>(&sP[pw * 2080 + i * 260 + col4]);
                v.x += p.x; v.y += p.y; v.z += p.z; v.w += p.w;
            }
            *reinterpret_cast<float4*>(&sQk[i * 260 + col4]) = v;
        }
    }
    __syncthreads();

    // ---- phase 2: wave w owns nodes b = 2w, 2w+1 ----
    const float4* f4 = reinterpret_cast<const float4*>(id2feat);
#pragma unroll
    for (int bb = 0; bb < 2; ++bb) {
        const int b = w * 2 + bb;
        float4 r[32];
#pragma unroll
        for (int j = 0; j < 32; ++j) r[j] = f4[(size_t)sIA[b * 32 + j] * 64 + l];
        float4 macc = make_float4(0.f, 0.f, 0.f, 0.f);
#pragma unroll
        for (int j = 0; j < 32; ++j) {
            const float4 v = f4[(size_t)sIM[b * 32 + j] * 64 + l];
            macc.x += v.x; macc.y += v.y; macc.z += v.z; macc.w += v.w;
        }
        const float4 q = *reinterpret_cast<const float4*>(&sQk[b * 260 + col4]);
        float sc[32];
#pragma unroll
        for (int j = 0; j < 32; ++j) {
            float p = q.x * r[j].x + q.y * r[j].y + q.z * r[j].z + q.w * r[j].w;
#pragma unroll
            for (int off = 32; off; off >>= 1) p += __shfl_xor(p, off);
            sc[j] = p;
        }
        float m = sc[0];
#pragma unroll
        for (int j = 1; j < 32; ++j) m = fmaxf(m, sc[j]);
        float sum = 0.f;
#pragma unroll
        for (int j = 0; j < 32; ++j) sum += __expf(sc[j] - m);
        const float inv = 1.0f / sum;
        float4 wa = make_float4(0.f, 0.f, 0.f, 0.f);
#pragma unroll
        for (int j = 0; j < 32; ++j) {
            const float wg = __expf(sc[j] - m);
            wa.x += wg * r[j].x; wa.y += wg * r[j].y;
            wa.z += wg * r[j].z; wa.w += wg * r[j].w;
        }
        const float mixv[4] = {wa.x * inv, wa.y * inv, wa.z * inv, wa.w * inv};
        const float mev[4] = {macc.x * (1.f / 32), macc.y * (1.f / 32),
                              macc.z * (1.f / 32), macc.w * (1.f / 32)};
#pragma unroll
        for (int c = 0; c < 4; ++c) {
            sAF[(col4 + c) * 12 + b] = mixv[c];          // mix -> AF cols [0,256)
            sAF[(256 + col4 + c) * 12 + b] = mev[c];     // mean -> AF cols [256,512)
        }
    }
    __syncthreads();

    // ---- phase 3: wave w does K-quarter [w*128, w*128+128) of final GEMM ----
#pragma unroll
    for (int i = 0; i < 8; ++i)
#pragma unroll
        for (int c = 0; c < 4; ++c) acc[i][c] = 0.f;
    {
        const int kbeg = w * 128;
        const float* Bp = Wfused + (size_t)kbeg * 256 + col4;
        float4 bufA[8], bufB[8];
#pragma unroll
        for (int j = 0; j < 8; ++j)
            bufA[j] = *reinterpret_cast<const float4*>(&Bp[(size_t)j * 256]);
        for (int kb = 0; kb < 128; kb += 16) {
#pragma unroll
            for (int j = 0; j < 8; ++j)
                bufB[j] = *reinterpret_cast<const float4*>(&Bp[(size_t)(kb + 8 + j) * 256]);
#pragma unroll
            for (int j = 0; j < 8; ++j) {
                const int k = kbeg + kb + j;
                const float4 a0 = *reinterpret_cast<const float4*>(&sAF[k * 12]);
                const float4 a1 = *reinterpret_cast<const float4*>(&sAF[k * 12 + 4]);
                FMA8(a0, a1, bufA[j]);
            }
            if (kb + 16 < 128) {
#pragma unroll
                for (int j = 0; j < 8; ++j)
                    bufA[j] = *reinterpret_cast<const float4*>(&Bp[(size_t)(kb + 16 + j) * 256]);
            }
#pragma unroll
            for (int j = 0; j < 8; ++j) {
                const int k = kbeg + kb + 8 + j;
                const float4 a0 = *reinterpret_cast<const float4*>(&sAF[k * 12]);
                const float4 a1 = *reinterpret_cast<const float4*>(&sAF[k * 12 + 4]);
                FMA8(a0, a1, bufB[j]);
            }
        }
    }
    if (w > 0) {
#pragma unroll
        for (int i = 0; i < 8; ++i)
            *reinterpret_cast<float4*>(&sP[(w - 1) * 2080 + i * 260 + col4]) =
                make_float4(acc[i][0], acc[i][1], acc[i][2], acc[i][3]);
    }
    __syncthreads();
    if (w == 0) {
        const float4 bf4 = *reinterpret_cast<const float4*>(&bfull[col4]);
#pragma unroll
        for (int i = 0; i < 8; ++i) {
            float v0 = acc[i][0] + bf4.x;
            float v1 = acc[i][1] + bf4.y;
            float v2 = acc[i][2] + bf4.z;
            float v3 = acc[i][3] + bf4.w;
#pragma unroll
            for (int pw = 0; pw < 3; ++pw) {
                const float4 p =
                    *reinterpret_cast<const float4*>(&sP[pw * 2080 + i * 260 + col4]);
                v0 += p.x; v1 += p.y; v2 += p.z; v3 += p.w;
            }
            v0 = tanhf(v0); v1 = tanhf(v1); v2 = tanhf(v2); v3 = tanhf(v3);
            float pw2 = v0 * v0 + v1 * v1 + v2 * v2 + v3 * v3;
#pragma unroll
            for (int off = 32; off; off >>= 1) pw2 += __shfl_xor(pw2, off);
            const float invn = 1.0f / fmaxf(sqrtf(pw2), 1e-12f);
            *reinterpret_cast<float4*>(&out[(size_t)(row0 + i) * 256 + col4]) =
                make_float4(v0 * invn, v1 * invn, v2 * invn, v3 * invn);
        }
    }
}

extern "C" void kernel_launch(void* const* d_in, const int* in_sizes, int n_in,
                              void* d_out, int out_size, void* d_ws, size_t ws_size,
                              hipStream_t stream) {
    const int* nodes      = (const int*)d_in[0];
    const int* neigh_mean = (const int*)d_in[1];
    const int* neigh_attn = (const int*)d_in[2];
    const float* id2feat  = (const float*)d_in[3];
    const float* Wm = (const float*)d_in[4];
    const float* bm = (const float*)d_in[5];
    const float* Wq = (const float*)d_in[6];
    const float* bq = (const float*)d_in[7];
    const float* Wk = (const float*)d_in[8];
    // d_in[9] = bk: cancels in softmax
    const float* Wv = (const float*)d_in[10];
    const float* bv = (const float*)d_in[11];
    const float* Wc = (const float*)d_in[12];
    const float* bc = (const float*)d_in[13];
    float* out = (float*)d_out;

    const int B = in_sizes[0];  // 4096

    float* ws    = (float*)d_ws;
    float* WkT   = ws;                 // 65536
    float* Wqk   = ws + 65536;         // 65536
    float* Wvc   = ws + 131072;        // 65536 } contiguous Wfused[512][256]
    float* Wmc   = ws + 196608;        // 65536 }
    float* bqk   = ws + 262144;        // 256
    float* bfull = ws + 262400;        // 256

    transpose256<<<dim3(8, 8), dim3(32, 8), 0, stream>>>(Wk, WkT);
    precompute3<<<dim3(32, 3), 256, 0, stream>>>(Wq, Wv, Wm, Wc, WkT, Wqk, Wvc, Wmc);
    bias_k<<<256, 256, 0, stream>>>(bq, bv, bm, bc, Wc, WkT, bqk, bfull);
    fused8<<<B / 8, 256, 0, stream>>>(id2feat, nodes, neigh_mean, neigh_attn,
                                      Wqk, bqk, Wvc /*Wfused*/, bfull, out);
}